// Round 1
// baseline (924.502 us; speedup 1.0000x reference)
//
#include <hip/hip_runtime.h>
#include <math.h>

#define F_IN 512
#define HID  16
#define NCLS 40

// ---------------- degree / norm ----------------

__global__ void k_init_deg(float* __restrict__ deg, int n) {
    int i = blockIdx.x * 256 + threadIdx.x;
    if (i < n) deg[i] = 1.0f;   // self-loop weight
}

__global__ void k_deg(const int* __restrict__ col, const float* __restrict__ w,
                      float* __restrict__ deg, int E) {
    int i = blockIdx.x * 256 + threadIdx.x;
    if (i < E) atomicAdd(&deg[col[i]], w[i]);
}

__global__ void k_dis(const float* __restrict__ deg, float* __restrict__ dis, int n) {
    int i = blockIdx.x * 256 + threadIdx.x;
    if (i < n) dis[i] = rsqrtf(deg[i]);
}

// ---------------- h1 = x @ W1  (N x 512  @  512 x 16) ----------------
// Block = 256 threads = 16 nodes x 16 outputs. W1 staged transposed+padded in
// LDS (bank stride 516 -> 2-way max, free). x read as float4, 16-lane
// broadcast per node row (L1 line reuse across k).

__global__ void k_xw1(const float* __restrict__ x, const float* __restrict__ W1,
                      float* __restrict__ h1, int N, int nGroups) {
    __shared__ float w1t[HID][F_IN + 4];
    for (int f = threadIdx.x; f < F_IN * HID; f += 256) {
        int k = f >> 4, h = f & 15;
        w1t[h][k] = W1[f];
    }
    __syncthreads();
    int nl = threadIdx.x >> 4;   // node within group, 0..15
    int h  = threadIdx.x & 15;   // output channel
    for (int g = blockIdx.x; g < nGroups; g += gridDim.x) {
        int n = g * 16 + nl;
        if (n < N) {
            const float4* xr = (const float4*)(x + (size_t)n * F_IN);
            float acc = 0.f;
            #pragma unroll 8
            for (int k4 = 0; k4 < F_IN / 4; ++k4) {
                float4 xv = xr[k4];
                const float* wp = &w1t[h][k4 * 4];
                acc = fmaf(xv.x, wp[0], acc);
                acc = fmaf(xv.y, wp[1], acc);
                acc = fmaf(xv.z, wp[2], acc);
                acc = fmaf(xv.w, wp[3], acc);
            }
            h1[(size_t)n * HID + h] = acc;
        }
    }
}

// ---------------- aggregation: dst = Ahat * src (16-dim) ----------------
// self-loop init: dst[n] = src[n] * dis[n]^2   (norm = dis*1*dis = 1/deg)

__global__ void k_selfinit(const float* __restrict__ src, const float* __restrict__ dis,
                           float* __restrict__ dst, int n16) {
    int i = blockIdx.x * 256 + threadIdx.x;
    if (i < n16) {
        float d = dis[i >> 4];
        dst[i] = src[i] * d * d;
    }
}

// one thread per (edge, h): 16 consecutive lanes share an edge -> broadcast
// index loads, coalesced 64B gather of src row, 16 consecutive atomics.
__global__ void k_scatter(const int* __restrict__ row, const int* __restrict__ col,
                          const float* __restrict__ w, const float* __restrict__ dis,
                          const float* __restrict__ src, float* __restrict__ dst, int E16) {
    int i = blockIdx.x * 256 + threadIdx.x;
    if (i < E16) {
        int e = i >> 4, h = i & 15;
        int r = row[e], c = col[e];
        float nrm = dis[r] * w[e] * dis[c];
        atomicAdd(&dst[c * HID + h], nrm * src[r * HID + h]);
    }
}

__global__ void k_relu_bias(const float* __restrict__ B, const float* __restrict__ b1,
                            float* __restrict__ A, int n16) {
    int i = blockIdx.x * 256 + threadIdx.x;
    if (i < n16) {
        float v = B[i] + b1[i & 15];
        A[i] = v > 0.f ? v : 0.f;
    }
}

// ---------------- final: out = log_softmax(agg2 @ W2 + b2) ----------------

__global__ void k_final(const float* __restrict__ B, const float* __restrict__ W2,
                        const float* __restrict__ b2, float* __restrict__ out, int N) {
    __shared__ float w2s[HID * NCLS];
    __shared__ float b2s[NCLS];
    for (int f = threadIdx.x; f < HID * NCLS; f += 256) w2s[f] = W2[f];
    if (threadIdx.x < NCLS) b2s[threadIdx.x] = b2[threadIdx.x];
    __syncthreads();
    int nd = blockIdx.x * 256 + threadIdx.x;
    if (nd < N) {
        float a[HID];
        const float4* ap = (const float4*)(B + (size_t)nd * HID);
        #pragma unroll
        for (int q = 0; q < 4; ++q) {
            float4 v = ap[q];
            a[q * 4 + 0] = v.x; a[q * 4 + 1] = v.y;
            a[q * 4 + 2] = v.z; a[q * 4 + 3] = v.w;
        }
        float y[NCLS];
        #pragma unroll
        for (int c = 0; c < NCLS; ++c) y[c] = b2s[c];
        #pragma unroll
        for (int h = 0; h < HID; ++h) {
            float av = a[h];
            #pragma unroll
            for (int c = 0; c < NCLS; ++c) y[c] = fmaf(av, w2s[h * NCLS + c], y[c]);
        }
        float m = y[0];
        #pragma unroll
        for (int c = 1; c < NCLS; ++c) m = fmaxf(m, y[c]);
        float s = 0.f;
        #pragma unroll
        for (int c = 0; c < NCLS; ++c) s += expf(y[c] - m);
        float base = m + logf(s);
        float* op = out + (size_t)nd * NCLS;
        #pragma unroll
        for (int c = 0; c < NCLS; ++c) op[c] = y[c] - base;
    }
}

// ---------------- launch ----------------

extern "C" void kernel_launch(void* const* d_in, const int* in_sizes, int n_in,
                              void* d_out, int out_size, void* d_ws, size_t ws_size,
                              hipStream_t stream) {
    const float* x  = (const float*)d_in[0];
    const int*   ei = (const int*)d_in[1];
    const float* ew = (const float*)d_in[2];
    const float* W1 = (const float*)d_in[3];
    const float* b1 = (const float*)d_in[4];
    const float* W2 = (const float*)d_in[5];
    const float* b2 = (const float*)d_in[6];
    float* out = (float*)d_out;

    int N = in_sizes[0] / F_IN;      // 100000
    int E = in_sizes[2];             // 3200000
    const int* row = ei;
    const int* col = ei + E;

    // workspace layout (floats): deg[N], dis[N], A[16N], B[16N]  ~13.6 MB
    float* ws  = (float*)d_ws;
    float* deg = ws;
    float* dis = ws + N;
    float* A   = ws + 2 * (size_t)N;         // h1, later z1
    float* Bb  = ws + 2 * (size_t)N + 16 * (size_t)N;  // agg buffers

    int n16 = N * HID;
    int E16 = E * HID;
    dim3 blk(256);

    // degree + norm
    k_init_deg<<<dim3((N + 255) / 256), blk, 0, stream>>>(deg, N);
    k_deg<<<dim3((E + 255) / 256), blk, 0, stream>>>(col, ew, deg, E);
    k_dis<<<dim3((N + 255) / 256), blk, 0, stream>>>(deg, dis, N);

    // h1 = x @ W1
    int nGroups = (N + 15) / 16;
    int g1 = nGroups < 2048 ? nGroups : 2048;
    k_xw1<<<dim3(g1), blk, 0, stream>>>(x, W1, A, N, nGroups);

    // agg1 = Ahat * h1 ; z1 = relu(agg1 + b1)
    k_selfinit<<<dim3((n16 + 255) / 256), blk, 0, stream>>>(A, dis, Bb, n16);
    k_scatter<<<dim3((E16 + 255) / 256), blk, 0, stream>>>(row, col, ew, dis, A, Bb, E16);
    k_relu_bias<<<dim3((n16 + 255) / 256), blk, 0, stream>>>(Bb, b1, A, n16);

    // agg2 = Ahat * z1
    k_selfinit<<<dim3((n16 + 255) / 256), blk, 0, stream>>>(A, dis, Bb, n16);
    k_scatter<<<dim3((E16 + 255) / 256), blk, 0, stream>>>(row, col, ew, dis, A, Bb, E16);

    // out = log_softmax(agg2 @ W2 + b2)
    k_final<<<dim3((N + 255) / 256), blk, 0, stream>>>(Bb, W2, b2, out, N);
}